// Round 5
// baseline (940.700 us; speedup 1.0000x reference)
//
#include <hip/hip_runtime.h>
#include <hip/hip_cooperative_groups.h>

namespace cg = cooperative_groups;

#define N_IMG 100000
#define C_CLS 1000
#define CP    1024    // padded class count
#define DIM   512     // att_dim == img_dim
#define HPROJ 256     // H
#define CAP   512     // per-class bucket capacity
#define GRID  512     // cooperative grid: 2 blocks/CU on 256 CUs

// ===========================================================================
// Cooperative mega-kernel phases
// ===========================================================================

// P3/P6: X = rownorm(A_eff @ Wm) written transposed to XnT[256][1024].
// Blocks 0..249, 4 rows each. A_eff = A0 rows, or (Q0+Q1+Q2+Q3)/rsum rows.
__device__ __forceinline__ void projnorm_phase(
    const float* __restrict__ A0, const float* __restrict__ Qp,
    const float* __restrict__ rsum, const float* __restrict__ Wm,
    float* __restrict__ XnT, char* smem, int t, int b)
{
    if (b >= 250) return;
    float* s_a = (float*)smem;                 // [4][512]
    float* red = (float*)(smem + 8192);        // [4][4]
    float* srn = (float*)(smem + 8192 + 64);   // [4]
    const int i0 = b * 4;
    for (int l = t; l < 512; l += 256) {       // 4 rows x 128 float4
        const int r = l >> 7, f = l & 127;
        const int row = i0 + r;
        float4 v;
        if (A0) {
            v = *(const float4*)(A0 + (size_t)row * DIM + 4 * f);
        } else {
            const float4 q0 = *(const float4*)(Qp + (size_t)row * DIM + 4 * f);
            const float4 q1 = *(const float4*)(Qp + (size_t)CP * DIM + (size_t)row * DIM + 4 * f);
            const float4 q2 = *(const float4*)(Qp + 2 * (size_t)CP * DIM + (size_t)row * DIM + 4 * f);
            const float4 q3 = *(const float4*)(Qp + 3 * (size_t)CP * DIM + (size_t)row * DIM + 4 * f);
            const float rs = 1.0f / rsum[row];
            v.x = (q0.x + q1.x + q2.x + q3.x) * rs;
            v.y = (q0.y + q1.y + q2.y + q3.y) * rs;
            v.z = (q0.z + q1.z + q2.z + q3.z) * rs;
            v.w = (q0.w + q1.w + q2.w + q3.w) * rs;
        }
        *(float4*)(s_a + r * 512 + 4 * f) = v;
    }
    __syncthreads();
    float acc[4] = {0.f, 0.f, 0.f, 0.f};
#pragma unroll 4
    for (int k = 0; k < 512; k += 4) {         // b128 LDS reads, 16 loads in flight
        const float w0 = Wm[(size_t)(k + 0) * HPROJ + t];
        const float w1 = Wm[(size_t)(k + 1) * HPROJ + t];
        const float w2 = Wm[(size_t)(k + 2) * HPROJ + t];
        const float w3 = Wm[(size_t)(k + 3) * HPROJ + t];
#pragma unroll
        for (int r = 0; r < 4; ++r) {
            const float4 av = *(const float4*)(s_a + r * 512 + k);
            acc[r] = fmaf(av.x, w0, acc[r]);
            acc[r] = fmaf(av.y, w1, acc[r]);
            acc[r] = fmaf(av.z, w2, acc[r]);
            acc[r] = fmaf(av.w, w3, acc[r]);
        }
    }
    float ss[4];
#pragma unroll
    for (int r = 0; r < 4; ++r) ss[r] = acc[r] * acc[r];
#pragma unroll
    for (int off = 32; off > 0; off >>= 1)
#pragma unroll
        for (int r = 0; r < 4; ++r) ss[r] += __shfl_down(ss[r], off);
    if ((t & 63) == 0) {
        const int wv = t >> 6;
#pragma unroll
        for (int r = 0; r < 4; ++r) red[r * 4 + wv] = ss[r];
    }
    __syncthreads();
    if (t < 4) srn[t] = rsqrtf(red[t * 4] + red[t * 4 + 1] + red[t * 4 + 2] + red[t * 4 + 3]);
    __syncthreads();
    float4 tv;
    tv.x = acc[0] * srn[0]; tv.y = acc[1] * srn[1];
    tv.z = acc[2] * srn[2]; tv.w = acc[3] * srn[3];
    *(float4*)(XnT + (size_t)t * CP + i0) = tv;
}

// P4/P7: WT[j][i] = maskexp(cos_ij) + fused row-sum (atomic, rsum pre-zeroed).
// 512 tiles: i-tile 64 (16 tiles) x j-tile 32 (32 tiles). Thread: 4i x 2j.
__device__ __forceinline__ void score_phase(
    const float* __restrict__ XnT, float* __restrict__ WT,
    float* __restrict__ rsum, char* smem, int t, int b)
{
    float (*Xi)[68]   = (float(*)[68])smem;                    // [64][68]
    float (*Xj)[36]   = (float(*)[36])(smem + 17408);          // [64][36]
    float (*s_rp)[17] = (float(*)[17])(smem + 17408 + 9216);   // [64][17]
    const int i0 = (b & 15) * 64;
    const int j0 = (b >> 4) * 32;
    const int tx = t & 15, ty = t >> 4;
    float a[4][2] = {};
    for (int ch = 0; ch < 4; ++ch) {
        const int kb = ch * 64;
        __syncthreads();
        for (int l = t; l < 1024; l += 256) {
            const int kk = l >> 4, f = l & 15;
            *(float4*)&Xi[kk][4 * f] = *(const float4*)(XnT + (size_t)(kb + kk) * CP + i0 + 4 * f);
        }
        for (int l = t; l < 512; l += 256) {
            const int kk = l >> 3, f = l & 7;
            *(float4*)&Xj[kk][4 * f] = *(const float4*)(XnT + (size_t)(kb + kk) * CP + j0 + 4 * f);
        }
        __syncthreads();
#pragma unroll 8
        for (int kk = 0; kk < 64; ++kk) {
            const float4 xi = *(const float4*)&Xi[kk][4 * tx];
            const float2 xj = *(const float2*)&Xj[kk][2 * ty];
            const float xiv[4] = {xi.x, xi.y, xi.z, xi.w};
#pragma unroll
            for (int iu = 0; iu < 4; ++iu) {
                a[iu][0] = fmaf(xiv[iu], xj.x, a[iu][0]);
                a[iu][1] = fmaf(xiv[iu], xj.y, a[iu][1]);
            }
        }
    }
    float rp[4] = {0.f, 0.f, 0.f, 0.f};
#pragma unroll
    for (int ju = 0; ju < 2; ++ju) {
        const int j = j0 + 2 * ty + ju;
        const bool jv = (j < C_CLS);
        float4 o;
#pragma unroll
        for (int iu = 0; iu < 4; ++iu) {
            const float d = a[iu][ju];
            const float w = (jv && d > 0.5f) ? __expf(10.f * d) : 0.f;
            ((float*)&o)[iu] = w;
            rp[iu] += w;
        }
        *(float4*)(WT + (size_t)j * CP + i0 + 4 * tx) = o;   // i-contiguous, coalesced
    }
    __syncthreads();
#pragma unroll
    for (int iu = 0; iu < 4; ++iu) s_rp[4 * tx + iu][ty] = rp[iu];
    __syncthreads();
    if (t < 64) {
        float s = 0.f;
#pragma unroll
        for (int q = 0; q < 16; ++q) s += s_rp[t][q];
        const int i = i0 + t;
        if (i < C_CLS) atomicAdd(&rsum[i], s);
    }
}

// P5/P8: Q[kz] = W @ Vg partial GEMM (split-K x4, chunk 256 each).
// 512 tiles: c-tile 64 (8) x i-tile 64 (16) x kz (4). Thread: 4i x 4c.
__device__ __forceinline__ void mm_phase(
    const float* __restrict__ WT, const float* __restrict__ V,
    const int* __restrict__ vidx, float* __restrict__ Qp, char* smem, int t, int b)
{
    float (*Wt)[68] = (float(*)[68])smem;             // [64][68] k x i
    float (*Vt)[68] = (float(*)[68])(smem + 17408);   // [64][68] k x c
    const int c0 = (b & 7) * 64;
    const int i0 = ((b >> 3) & 15) * 64;
    const int kz = b >> 7;
    const int tx = t & 15, ty = t >> 4;
    float a[4][4] = {};
    for (int ch = 0; ch < 4; ++ch) {
        const int kb = kz * 256 + ch * 64;
        __syncthreads();
        for (int l = t; l < 1024; l += 256) {
            const int kk = l >> 4, f = l & 15;
            *(float4*)&Wt[kk][4 * f] = *(const float4*)(WT + (size_t)(kb + kk) * CP + i0 + 4 * f);
            const int jc = min(kb + kk, C_CLS - 1);   // WT rows >=1000 are zeros
            const int vr = vidx ? vidx[jc] : jc;
            *(float4*)&Vt[kk][4 * f] = *(const float4*)(V + (size_t)vr * DIM + c0 + 4 * f);
        }
        __syncthreads();
#pragma unroll 4
        for (int kk = 0; kk < 64; ++kk) {
            const float4 w = *(const float4*)&Wt[kk][4 * ty];
            const float4 v = *(const float4*)&Vt[kk][4 * tx];
            const float wv[4] = {w.x, w.y, w.z, w.w};
            const float vv[4] = {v.x, v.y, v.z, v.w};
#pragma unroll
            for (int iu = 0; iu < 4; ++iu)
#pragma unroll
                for (int cu = 0; cu < 4; ++cu)
                    a[iu][cu] = fmaf(wv[iu], vv[cu], a[iu][cu]);
        }
    }
    float* dst = Qp + (size_t)kz * CP * DIM;
#pragma unroll
    for (int iu = 0; iu < 4; ++iu) {
        const int i = i0 + 4 * ty + iu;
        float4 o = {a[iu][0], a[iu][1], a[iu][2], a[iu][3]};
        *(float4*)(dst + (size_t)i * DIM + c0 + 4 * tx) = o;
    }
}

__global__ __launch_bounds__(256, 2) void mega_kernel(
    const float* __restrict__ image_feats,
    const float* __restrict__ attributes,
    const float* __restrict__ att_g,
    const float* __restrict__ att_h,
    const int*   __restrict__ labels,
    const int*   __restrict__ tpl,
    float*       __restrict__ out,
    float* protos, float* XnT, float* WT, float* Qp,
    int* cnt, float* rsum1, float* rsum2, int* perm)
{
    cg::grid_group gg = cg::this_grid();
    __shared__ __align__(16) char smem[34816];
    const int t  = threadIdx.x;
    const int b  = blockIdx.x;
    const int g0 = b * 256 + t;

    // ---- P0: zero counters ----
    if (g0 < 1024) { cnt[g0] = 0; rsum1[g0] = 0.f; rsum2[g0] = 0.f; }
    gg.sync();

    // ---- P1: bucket labels ----
    if (g0 < N_IMG) {
        const int c = labels[g0];
        const int p = atomicAdd(&cnt[c], 1);
        if (p < CAP) perm[c * CAP + p] = g0;
    }
    gg.sync();

    // ---- P2: per-class mean (gather) ----
    {
        int*    s_list = (int*)smem;
        float4* s_acc  = (float4*)(smem + 2048);
        for (int c = b; c < C_CLS; c += GRID) {
            __syncthreads();
            const int n = min(cnt[c], CAP);
            for (int m = t; m < n; m += 256) s_list[m] = perm[c * CAP + m];
            __syncthreads();
            const int half = t >> 7;
            const int tc   = t & 127;
            float4 a0 = {0,0,0,0}, a1 = {0,0,0,0}, a2 = {0,0,0,0}, a3 = {0,0,0,0};
            int m = half;
            for (; m + 6 < n; m += 8) {
                const float4 v0 = *(const float4*)(image_feats + (size_t)s_list[m]     * DIM + 4 * tc);
                const float4 v1 = *(const float4*)(image_feats + (size_t)s_list[m + 2] * DIM + 4 * tc);
                const float4 v2 = *(const float4*)(image_feats + (size_t)s_list[m + 4] * DIM + 4 * tc);
                const float4 v3 = *(const float4*)(image_feats + (size_t)s_list[m + 6] * DIM + 4 * tc);
                a0.x += v0.x; a0.y += v0.y; a0.z += v0.z; a0.w += v0.w;
                a1.x += v1.x; a1.y += v1.y; a1.z += v1.z; a1.w += v1.w;
                a2.x += v2.x; a2.y += v2.y; a2.z += v2.z; a2.w += v2.w;
                a3.x += v3.x; a3.y += v3.y; a3.z += v3.z; a3.w += v3.w;
            }
            for (; m < n; m += 2) {
                const float4 v0 = *(const float4*)(image_feats + (size_t)s_list[m] * DIM + 4 * tc);
                a0.x += v0.x; a0.y += v0.y; a0.z += v0.z; a0.w += v0.w;
            }
            a0.x += a1.x + a2.x + a3.x; a0.y += a1.y + a2.y + a3.y;
            a0.z += a1.z + a2.z + a3.z; a0.w += a1.w + a2.w + a3.w;
            if (half) s_acc[tc] = a0;
            __syncthreads();
            if (!half) {
                const float4 o = s_acc[tc];
                const float inv = 1.0f / (float)n;
                float4 r;
                r.x = (a0.x + o.x) * inv; r.y = (a0.y + o.y) * inv;
                r.z = (a0.z + o.z) * inv; r.w = (a0.w + o.w) * inv;
                *(float4*)(protos + (size_t)c * DIM + 4 * tc) = r;
            }
        }
    }
    gg.sync();

    // ---- stage 1 ----
    projnorm_phase(attributes, nullptr, nullptr, att_h, XnT, smem, t, b);
    gg.sync();
    score_phase(XnT, WT, rsum1, smem, t, b);
    gg.sync();
    mm_phase(WT, attributes, nullptr, Qp, smem, t, b);
    gg.sync();

    // ---- stage 2 (combine of stage-1 fused into projnorm) ----
    projnorm_phase(nullptr, Qp, rsum1, att_g, XnT, smem, t, b);
    gg.sync();
    score_phase(XnT, WT, rsum2, smem, t, b);
    gg.sync();
    mm_phase(WT, protos, tpl, Qp, smem, t, b);
    gg.sync();

    // ---- P9: final combine ----
    if (g0 < C_CLS * DIM / 4) {
        const int i = g0 >> 7;
        const float4 q0 = *(const float4*)(Qp + 4 * (size_t)g0);
        const float4 q1 = *(const float4*)(Qp + (size_t)CP * DIM + 4 * (size_t)g0);
        const float4 q2 = *(const float4*)(Qp + 2 * (size_t)CP * DIM + 4 * (size_t)g0);
        const float4 q3 = *(const float4*)(Qp + 3 * (size_t)CP * DIM + 4 * (size_t)g0);
        const float s = 1.0f / rsum2[i];
        float4 o;
        o.x = s * (q0.x + q1.x + q2.x + q3.x);
        o.y = s * (q0.y + q1.y + q2.y + q3.y);
        o.z = s * (q0.z + q1.z + q2.z + q3.z);
        o.w = s * (q0.w + q1.w + q2.w + q3.w);
        *(float4*)(out + 4 * (size_t)g0) = o;
    }
}

// ===========================================================================
// Fallback path (round-4 kernels) — used only if cooperative launch fails.
// ===========================================================================
__global__ __launch_bounds__(256) void fill_kernel(
    const int* __restrict__ labels, int* __restrict__ cnt,
    int* __restrict__ perm, int n)
{
    const int i = blockIdx.x * 256 + threadIdx.x;
    if (i < n) {
        const int c = labels[i];
        const int p = atomicAdd(&cnt[c], 1);
        if (p < CAP) perm[c * CAP + p] = i;
    }
}

__global__ __launch_bounds__(256) void gather_kernel(
    const float* __restrict__ image_feats, const int* __restrict__ cnt,
    const int* __restrict__ perm, float* __restrict__ protos)
{
    __shared__ int    s_list[CAP];
    __shared__ float4 s_acc[128];
    const int c = blockIdx.x;
    const int t = threadIdx.x;
    const int n = min(cnt[c], CAP);
    for (int m = t; m < n; m += 256) s_list[m] = perm[c * CAP + m];
    __syncthreads();
    const int half = t >> 7;
    const int tc   = t & 127;
    float4 a0 = {0,0,0,0}, a1 = {0,0,0,0};
    int m = half;
    for (; m + 2 < n; m += 4) {
        const float4 v0 = *(const float4*)(image_feats + (size_t)s_list[m]     * DIM + 4 * tc);
        const float4 v1 = *(const float4*)(image_feats + (size_t)s_list[m + 2] * DIM + 4 * tc);
        a0.x += v0.x; a0.y += v0.y; a0.z += v0.z; a0.w += v0.w;
        a1.x += v1.x; a1.y += v1.y; a1.z += v1.z; a1.w += v1.w;
    }
    for (; m < n; m += 2) {
        const float4 v0 = *(const float4*)(image_feats + (size_t)s_list[m] * DIM + 4 * tc);
        a0.x += v0.x; a0.y += v0.y; a0.z += v0.z; a0.w += v0.w;
    }
    a0.x += a1.x; a0.y += a1.y; a0.z += a1.z; a0.w += a1.w;
    if (half) s_acc[tc] = a0;
    __syncthreads();
    if (!half) {
        const float4 o = s_acc[tc];
        const float inv = 1.0f / (float)n;
        float4 r;
        r.x = (a0.x + o.x) * inv; r.y = (a0.y + o.y) * inv;
        r.z = (a0.z + o.z) * inv; r.w = (a0.w + o.w) * inv;
        *(float4*)(protos + (size_t)c * DIM + 4 * tc) = r;
    }
}

__global__ __launch_bounds__(256) void proj_kernel(
    const float* __restrict__ A0, const float* __restrict__ Qp,
    const float* __restrict__ rsum, const float* __restrict__ Wm,
    float* __restrict__ P)
{
    __shared__ float At[64][34];
    __shared__ float Wt[64][36];
    const int t  = threadIdx.x;
    const int j0 = blockIdx.x * 32;
    const int i0 = blockIdx.y * 32;
    const int kz = blockIdx.z;
    const int tx = t & 15, ty = t >> 4;
    float a00 = 0.f, a01 = 0.f, a10 = 0.f, a11 = 0.f;
    for (int ch = 0; ch < 4; ++ch) {
        const int kb = kz * 256 + ch * 64;
        __syncthreads();
        for (int l = t; l < 512; l += 256) {
            const int r = l >> 4, f = l & 15;
            const int row = min(i0 + r, C_CLS - 1);
            float4 v;
            if (A0) {
                v = *(const float4*)(A0 + (size_t)row * DIM + kb + 4 * f);
            } else {
                const float4 q0 = *(const float4*)(Qp + (size_t)row * DIM + kb + 4 * f);
                const float4 q1 = *(const float4*)(Qp + (size_t)CP * DIM + (size_t)row * DIM + kb + 4 * f);
                const float rs = 1.0f / rsum[row];
                v.x = (q0.x + q1.x) * rs; v.y = (q0.y + q1.y) * rs;
                v.z = (q0.z + q1.z) * rs; v.w = (q0.w + q1.w) * rs;
            }
            At[4*f+0][r] = v.x; At[4*f+1][r] = v.y; At[4*f+2][r] = v.z; At[4*f+3][r] = v.w;
        }
        for (int l = t; l < 512; l += 256) {
            const int kk = l >> 3, f = l & 7;
            *(float4*)&Wt[kk][4*f] = *(const float4*)(Wm + (size_t)(kb + kk) * HPROJ + j0 + 4 * f);
        }
        __syncthreads();
#pragma unroll 8
        for (int kk = 0; kk < 64; ++kk) {
            const float2 a = *(const float2*)&At[kk][2 * ty];
            const float2 bv = *(const float2*)&Wt[kk][2 * tx];
            a00 = fmaf(a.x, bv.x, a00); a01 = fmaf(a.x, bv.y, a01);
            a10 = fmaf(a.y, bv.x, a10); a11 = fmaf(a.y, bv.y, a11);
        }
    }
    float* dst = P + (size_t)kz * CP * HPROJ;
    const int i = i0 + 2 * ty;
    *(float2*)(dst + (size_t)i * HPROJ + j0 + 2 * tx) = make_float2(a00, a01);
    *(float2*)(dst + (size_t)(i + 1) * HPROJ + j0 + 2 * tx) = make_float2(a10, a11);
}

__global__ __launch_bounds__(256) void norm_kernel(
    const float* __restrict__ P, float* __restrict__ XnT)
{
    __shared__ float red[4][4];
    __shared__ float srn[4];
    const int i0 = blockIdx.x * 4;
    const int t  = threadIdx.x;
    float x[4], ss[4];
#pragma unroll
    for (int u = 0; u < 4; ++u) {
        x[u] = P[(size_t)(i0 + u) * HPROJ + t]
             + P[(size_t)CP * HPROJ + (size_t)(i0 + u) * HPROJ + t];
        ss[u] = x[u] * x[u];
    }
#pragma unroll
    for (int off = 32; off > 0; off >>= 1)
#pragma unroll
        for (int u = 0; u < 4; ++u) ss[u] += __shfl_down(ss[u], off);
    if ((t & 63) == 0) {
        const int wv = t >> 6;
#pragma unroll
        for (int u = 0; u < 4; ++u) red[u][wv] = ss[u];
    }
    __syncthreads();
    if (t < 4) srn[t] = rsqrtf(red[t][0] + red[t][1] + red[t][2] + red[t][3]);
    __syncthreads();
    float4 tv;
    tv.x = x[0] * srn[0]; tv.y = x[1] * srn[1];
    tv.z = x[2] * srn[2]; tv.w = x[3] * srn[3];
    *(float4*)(XnT + (size_t)t * CP + i0) = tv;
}

__global__ __launch_bounds__(256) void score_kernel(
    const float* __restrict__ XnT, float* __restrict__ WT,
    float* __restrict__ rsum)
{
    __shared__ __align__(16) char smem[34816];
    score_phase(XnT, WT, rsum, smem, threadIdx.x, blockIdx.x);
}

__global__ __launch_bounds__(256) void mmf_kernel(
    const float* __restrict__ WT, const float* __restrict__ V,
    const int* __restrict__ vidx, float* __restrict__ Qp)
{
    __shared__ __align__(16) char smem[34816];
    mm_phase(WT, V, vidx, Qp, smem, threadIdx.x, blockIdx.x);
}

__global__ __launch_bounds__(256) void combine_kernel(
    const float* __restrict__ Qp, const float* __restrict__ rsum,
    float* __restrict__ Out)
{
    const int g = blockIdx.x * 256 + threadIdx.x;
    if (g < C_CLS * DIM / 4) {
        const int i = g >> 7;
        const float4 q0 = *(const float4*)(Qp + 4 * (size_t)g);
        const float4 q1 = *(const float4*)(Qp + (size_t)CP * DIM + 4 * (size_t)g);
        const float4 q2 = *(const float4*)(Qp + 2 * (size_t)CP * DIM + 4 * (size_t)g);
        const float4 q3 = *(const float4*)(Qp + 3 * (size_t)CP * DIM + 4 * (size_t)g);
        const float s = 1.0f / rsum[i];
        float4 o;
        o.x = s * (q0.x + q1.x + q2.x + q3.x);
        o.y = s * (q0.y + q1.y + q2.y + q3.y);
        o.z = s * (q0.z + q1.z + q2.z + q3.z);
        o.w = s * (q0.w + q1.w + q2.w + q3.w);
        *(float4*)(Out + 4 * (size_t)g) = o;
    }
}

__global__ __launch_bounds__(256) void projnorm_kernel(
    const float* __restrict__ A0, const float* __restrict__ Qp,
    const float* __restrict__ rsum, const float* __restrict__ Wm,
    float* __restrict__ XnT)
{
    __shared__ __align__(16) char smem[34816];
    projnorm_phase(A0, Qp, rsum, Wm, XnT, smem, threadIdx.x, blockIdx.x);
}

// ---------------------------------------------------------------------------
extern "C" void kernel_launch(void* const* d_in, const int* in_sizes, int n_in,
                              void* d_out, int out_size, void* d_ws, size_t ws_size,
                              hipStream_t stream) {
    const float* image_feats = (const float*)d_in[0];  // [100000, 512]
    const float* attributes  = (const float*)d_in[1];  // [1000, 512]
    const float* att_g       = (const float*)d_in[2];  // [512, 256]
    const float* att_h       = (const float*)d_in[3];  // [512, 256]
    const int*   labels      = (const int*)d_in[4];    // [100000]
    const int*   tpl         = (const int*)d_in[5];    // [1000]
    float* out = (float*)d_out;                        // [1000, 512]

    float* ws     = (float*)d_ws;
    float* protos = ws;                        // 512000
    float* XnT    = protos + 512000;           // 262144
    float* WT     = XnT + 262144;              // 1048576
    float* Qpart  = WT + 1048576;              // 2097152 (4 split-K parts)
    int*   cnt    = (int*)(Qpart + 2097152);   // 1024
    float* rsum1  = (float*)(cnt + 1024);      // 1024
    float* rsum2  = rsum1 + 1024;              // 1024
    int*   perm   = (int*)(rsum2 + 1024);      // 512000

    void* args[] = {
        (void*)&image_feats, (void*)&attributes, (void*)&att_g, (void*)&att_h,
        (void*)&labels, (void*)&tpl, (void*)&out,
        (void*)&protos, (void*)&XnT, (void*)&WT, (void*)&Qpart,
        (void*)&cnt, (void*)&rsum1, (void*)&rsum2, (void*)&perm};
    hipError_t err = hipLaunchCooperativeKernel(
        reinterpret_cast<void*>(mega_kernel), dim3(GRID), dim3(256),
        args, 0, stream);

    if (err != hipSuccess) {
        // Fallback: multi-kernel chain (same math, split-K x4 mm + score/mm
        // phase bodies shared with the cooperative kernel).
        hipMemsetAsync(cnt, 0, 3 * 1024 * sizeof(int), stream);
        fill_kernel<<<(N_IMG + 255) / 256, 256, 0, stream>>>(labels, cnt, perm, N_IMG);
        gather_kernel<<<C_CLS, 256, 0, stream>>>(image_feats, cnt, perm, protos);
        projnorm_kernel<<<250, 256, 0, stream>>>(attributes, nullptr, nullptr, att_h, XnT);
        score_kernel<<<GRID, 256, 0, stream>>>(XnT, WT, rsum1);
        mmf_kernel<<<GRID, 256, 0, stream>>>(WT, attributes, nullptr, Qpart);
        projnorm_kernel<<<250, 256, 0, stream>>>(nullptr, Qpart, rsum1, att_g, XnT);
        score_kernel<<<GRID, 256, 0, stream>>>(XnT, WT, rsum2);
        mmf_kernel<<<GRID, 256, 0, stream>>>(WT, protos, tpl, Qpart);
        combine_kernel<<<500, 256, 0, stream>>>(Qpart, rsum2, out);
    }
}